// Round 7
// baseline (235.632 us; speedup 1.0000x reference)
//
#include <hip/hip_runtime.h>
#include <stdint.h>

typedef _Float16 v8h __attribute__((ext_vector_type(8)));
typedef _Float16 v4h __attribute__((ext_vector_type(4)));
typedef float v4f __attribute__((ext_vector_type(4)));

#define BB 4
#define LL 2048
#define TOPK 32
#define NF 416      // 16 pos + 16 R0 + 24*16 pair RBF
#define NOUT 128
#define NCAND 128
#define FBS 72      // Fb chunk stride in halves (144 B, 16B-aligned)

__device__ __constant__ int c_PA[24] = {0,2,3,4,1,1,1,1,0,0,0,4,4,3,0,2,3,4,2,3,4,2,3,2};
__device__ __constant__ int c_PB[24] = {0,2,3,4,0,2,3,4,2,3,4,2,3,2,1,1,1,1,0,0,0,4,4,3};

// ws layout (bytes)
#define OFF_ATOMS 0u            // B*L*16 f32 (4x float4/residue) = 524288 B
#define OFF_CA    524288u       // B*L float4                     = 131072 B
#define OFF_WT    655360u       // 128*416 f16                    = 106496 B

// wave-private monotone bin: exponent + 4 mantissa bits (16 bins/octave).
// bin = (bits>>19) - 1870: self-distance (1e-3) -> bin 2; d=1.7 -> ~173;
// d=40 -> ~246; clamp 511 unreachable in practice.
static __device__ inline int wbin(unsigned u) {
  int v = (int)(u >> 19) - 1870;
  v = v < 0 ? 0 : v;
  return v > 511 ? 511 : v;
}

// np-bit-matched distance: ((dx*dx+dy*dy)+dz*dz)+1e-6, no fma, exact sqrt
static __device__ inline float dist_np(float4 a, float4 b) {
#pragma clang fp contract(off)
  float dx = a.x - b.x, dy = a.y - b.y, dz = a.z - b.z;
  float s = ((dx * dx + dy * dy) + dz * dz) + 1e-6f;
  return sqrtf(s);
}

static __device__ inline unsigned long long umin64(unsigned long long a, unsigned long long b) {
  return a < b ? a : b;
}
static __device__ inline unsigned long long umax64(unsigned long long a, unsigned long long b) {
  return a > b ? a : b;
}

// windowed RBF: exp(-((d-mu_m)/1.25)^2), mu_m = 2 + (4/3)m, m=0..15.
// Only 8 consecutive m give values >= 2^-25 (f16-visible); rest exactly 0.
static __device__ inline void rbf16w(float d, _Float16* dst) {
  v8h z = {};
  *(v8h*)dst = z;
  *(v8h*)(dst + 8) = z;
  float m0f = ceilf((d - 7.204f) * 0.75f);
  m0f = fmaxf(0.0f, fminf(8.0f, m0f));
  const float C  = 0.96089780f;   // sqrt(0.64 * log2(e))
  const float SC = 1.28119707f;   // (4/3) * C
  float a0 = d * C - 1.92179560f - m0f * SC;  // a at m = m0
  _Float16* p = dst + (int)m0f;
#pragma unroll
  for (int t = 0; t < 8; ++t) {
    float a = a0 - (float)t * SC;
    float v = __builtin_amdgcn_exp2f(-(a * a));
    p[t] = (_Float16)v;
  }
}

static __device__ inline float pdist(const float* qa, const float* nb, int pp) {
  int ia = c_PA[pp] * 3, ib = c_PB[pp] * 3;
  float dx = qa[ia] - nb[ib];
  float dy = qa[ia + 1] - nb[ib + 1];
  float dz = qa[ia + 2] - nb[ib + 2];
  return sqrtf(dx * dx + dy * dy + dz * dz + 1e-6f);
}

// ---------------- prep: atoms (16f rows), compact Ca float4, W_edge -> f16 T ----------------
__global__ __launch_bounds__(256) void prep_kernel(const float* __restrict__ X,
                                                   const float* __restrict__ W_edge,
                                                   float4* __restrict__ atomsP,
                                                   float4* __restrict__ CaP,
                                                   _Float16* __restrict__ Wt) {
  int idx = blockIdx.x * 256 + threadIdx.x;
  if (idx < BB * LL) {
    const float* xp = X + (size_t)idx * 12;
    float Nx = xp[0], Ny = xp[1], Nz = xp[2];
    float Cax = xp[3], Cay = xp[4], Caz = xp[5];
    float Cx = xp[6], Cy = xp[7], Cz = xp[8];
    float Ox = xp[9], Oy = xp[10], Oz = xp[11];
    float bx = Cax - Nx, by = Cay - Ny, bz = Caz - Nz;
    float cx = Cx - Cax, cy = Cy - Cay, cz = Cz - Caz;
    float ax = by * cz - bz * cy;
    float ay = bz * cx - bx * cz;
    float az = bx * cy - by * cx;
    float Cbx = -0.58273431f * ax + 0.56802827f * bx - 0.54067466f * cx + Cax;
    float Cby = -0.58273431f * ay + 0.56802827f * by - 0.54067466f * cy + Cay;
    float Cbz = -0.58273431f * az + 0.56802827f * bz - 0.54067466f * cz + Caz;
    // layout: [N(3) Ca(3) C(3) O(3) Cb(3) pad] as 4x float4
    atomsP[(size_t)idx * 4 + 0] = make_float4(Nx, Ny, Nz, Cax);
    atomsP[(size_t)idx * 4 + 1] = make_float4(Cay, Caz, Cx, Cy);
    atomsP[(size_t)idx * 4 + 2] = make_float4(Cz, Ox, Oy, Oz);
    atomsP[(size_t)idx * 4 + 3] = make_float4(Cbx, Cby, Cbz, 0.f);
    CaP[idx] = make_float4(Cax, Cay, Caz, 0.f);
  } else {
    int t = idx - BB * LL;
    if (t < NOUT * NF) {
      int n = t / NF;
      int k = t - n * NF;
      Wt[t] = (_Float16)W_edge[(size_t)k * NOUT + n];  // Wt[n][k] = W_edge[k][n]
    }
  }
}

// ---------------- top-32: ONE WAVE PER QUERY, zero block barriers.
// Wave-private 512-bin hist + shfl scan + ballot crossing + bitonic sort.
// R7 fix: distance loads batched 8x4 with sched_barrier fences so LLVM cannot
// hoist all 32 float4 loads into flight at once (was ~128 VGPRs of in-flight
// loads -> occupancy collapse -> exposed latency). __launch_bounds__(256,5)
// caps VGPR at ~102 (live set ~70, no spill) -> 20 waves/CU. ----------------
__global__ __launch_bounds__(256, 5) void topk_kernel(const float4* __restrict__ CaP,
                                                      float* __restrict__ outIdx) {
  __shared__ int hist[4][512];                   // 8 KB
  __shared__ unsigned long long cand[4][NCAND];  // 4 KB
  __shared__ int cnt[4];

  int tid = threadIdx.x;
  int lane = tid & 63, wid = tid >> 6;
  int q = blockIdx.x * 4 + wid;     // global query id
  int b = q >> 11;
  int i = q & (LL - 1);

  int* h = hist[wid];
  unsigned long long* cd = cand[wid];

  {  // zero hist (8 ints/lane) + init cand + cnt
    int4 z = make_int4(0, 0, 0, 0);
    ((int4*)h)[lane] = z;
    ((int4*)h)[lane + 64] = z;
    cd[lane] = ~0ull;
    cd[lane + 64] = ~0ull;
    if (lane == 0) cnt[wid] = 0;
  }

  const float4* Cb_ = CaP + (size_t)b * LL;
  float4 ci = Cb_[i];
  unsigned db[32];
#pragma unroll
  for (int bt = 0; bt < 8; ++bt) {
    float4 v0 = Cb_[lane + ((bt * 4 + 0) << 6)];
    float4 v1 = Cb_[lane + ((bt * 4 + 1) << 6)];
    float4 v2 = Cb_[lane + ((bt * 4 + 2) << 6)];
    float4 v3 = Cb_[lane + ((bt * 4 + 3) << 6)];
    db[bt * 4 + 0] = __float_as_uint(dist_np(ci, v0));
    db[bt * 4 + 1] = __float_as_uint(dist_np(ci, v1));
    db[bt * 4 + 2] = __float_as_uint(dist_np(ci, v2));
    db[bt * 4 + 3] = __float_as_uint(dist_np(ci, v3));
    __builtin_amdgcn_sched_barrier(0);  // pin: next batch's loads stay below
  }
  asm volatile("s_waitcnt lgkmcnt(0)" ::: "memory");  // zero/init done (wave-local)
#pragma unroll
  for (int t = 0; t < 32; ++t) {
    atomicAdd(&h[wbin(db[t])], 1);
  }
  asm volatile("s_waitcnt lgkmcnt(0)" ::: "memory");  // hist complete (wave-local)

  // scan: lane owns bins [lane*8, lane*8+8)
  int pb[8];
  int psum = 0;
  {
    int4 a0 = ((int4*)h)[lane * 2];
    int4 a1 = ((int4*)h)[lane * 2 + 1];
    pb[0] = a0.x; pb[1] = a0.y; pb[2] = a0.z; pb[3] = a0.w;
    pb[4] = a1.x; pb[5] = a1.y; pb[6] = a1.z; pb[7] = a1.w;
#pragma unroll
    for (int t = 0; t < 8; ++t) psum += pb[t];
  }
  int incl = psum;
#pragma unroll
  for (int off = 1; off < 64; off <<= 1) {
    int o = __shfl_up(incl, off);
    if (lane >= off) incl += o;
  }
  int base = incl - psum;  // exclusive prefix over 64 lane-ranges
  bool cross = (base < TOPK && incl >= TOPK);  // exactly one lane true
  int cb_local = 511;
  if (cross) {
    int run = base;
#pragma unroll
    for (int t = 0; t < 8; ++t) {
      if (run < TOPK && run + pb[t] >= TOPK) { cb_local = lane * 8 + t; break; }
      run += pb[t];
    }
  }
  unsigned long long cm = __ballot(cross);
  int src = __ffsll(cm) - 1;
  int cb = __shfl(cb_local, src);

  // collect keys with bin <= cb
#pragma unroll
  for (int t = 0; t < 32; ++t) {
    if (wbin(db[t]) <= cb) {
      int slot = atomicAdd(&cnt[wid], 1);
      if (slot < NCAND)
        cd[slot] = ((unsigned long long)db[t] << 32) | (unsigned)(lane + (t << 6));
    }
  }
  asm volatile("s_waitcnt lgkmcnt(0)" ::: "memory");  // collect visible (wave-local)

  int C = cnt[wid];
  unsigned long long x = cd[lane];
  if (C <= 64) {  // typical: C ~ 36-45; 21-step single-width bitonic sort
#pragma unroll
    for (int k = 2; k <= 64; k <<= 1) {
#pragma unroll
      for (int j = k >> 1; j >= 1; j >>= 1) {
        unsigned long long px = __shfl_xor(x, j);
        bool up = ((lane & k) == 0);
        bool low = ((lane & j) == 0);
        x = (low == up) ? umin64(x, px) : umax64(x, px);
      }
    }
  } else {  // fallback: full 128-candidate sort, 2/lane
    unsigned long long y = cd[lane + 64];
#pragma unroll
    for (int k = 2; k <= 128; k <<= 1) {
#pragma unroll
      for (int j = 64; j >= 1; j >>= 1) {
        if (j >= k) continue;
        if (j == 64) {
          unsigned long long mn = umin64(x, y), mx = umax64(x, y);
          x = mn; y = mx;
        } else {
          unsigned long long px = __shfl_xor(x, j);
          bool upx = ((lane & k) == 0);
          bool lowx = ((lane & j) == 0);
          x = (lowx == upx) ? umin64(x, px) : umax64(x, px);
          unsigned long long py = __shfl_xor(y, j);
          bool upy = (((lane + 64) & k) == 0);
          y = (lowx == upy) ? umin64(y, py) : umax64(y, py);
        }
      }
    }
  }
  if (lane < TOPK) {
    int j = (int)(x & 0xffffffffull);
    outIdx[(size_t)q * TOPK + lane] = (float)j;
  }
}

// ---------------- 4 residues/block: features -> f16 MFMA GEMM, double-buffered 64-col
// K-chunks so feature VALU (exp2) overlaps MFMA; LDS <= 54613 B -> 3 blocks/CU.
// (round-3 verified version, 79.8 us — do not re-pipeline: spills, see R5) ----------------
__global__ __launch_bounds__(512, 6) void edge_kernel(
    const float4* __restrict__ atomsP, const float4* __restrict__ CaP,
    const _Float16* __restrict__ Wt, const float* __restrict__ outIdxF,
    const int* __restrict__ ridx, const int* __restrict__ chain,
    const float* __restrict__ W_pos, const float* __restrict__ b_pos,
    const float* __restrict__ gamma, const float* __restrict__ beta,
    float* __restrict__ outE) {
  __shared__ __align__(16) _Float16 Fb[2][128][FBS];  // 36864 B, ping-pong K-chunks
  __shared__ float na_f[128][17];                     // neighbor atoms, padded stride
  __shared__ float qa_f[4][16];                       // query atoms per residue
  __shared__ float dnbr_s[128];
  __shared__ int dpos_s[128];
  __shared__ int nidx_s[128];
  __shared__ float partS[128][5];
  __shared__ float partQ[128][5];
  __shared__ float2 mr[128];

  int bid = blockIdx.x;          // group of 4 residues
  int b = bid >> 9;
  int tid = threadIdx.x;
  int g0 = bid * 4;              // first global residue (b*LL + i0 == bid*4)

  if (tid < 128) {
    int r = tid >> 5;
    int j = (int)outIdxF[(size_t)bid * 128 + tid];
    nidx_s[tid] = j;
    dnbr_s[tid] = dist_np(CaP[g0 + r], CaP[(size_t)b * LL + j]);
    int ri = ridx[g0 + r], rj = ridx[b * LL + j];
    int off = ri - rj + 32;
    off = off < 0 ? 0 : (off > 64 ? 64 : off);
    dpos_s[tid] = (chain[g0 + r] == chain[b * LL + j]) ? off : 65;
  } else if (tid < 144) {
    int q16 = tid - 128;
    int r = q16 >> 2, q = q16 & 3;
    float4 v = atomsP[(size_t)(g0 + r) * 4 + q];
    qa_f[r][q * 4 + 0] = v.x; qa_f[r][q * 4 + 1] = v.y;
    qa_f[r][q * 4 + 2] = v.z; qa_f[r][q * 4 + 3] = v.w;
  }
  __syncthreads();

  int e = tid >> 2, g = tid & 3;
  int rr = e >> 5;
  {  // neighbor atoms: one coalesced float4/thread; readers of na_f[e] are the same quad
    float4 v = atomsP[((size_t)b * LL + nidx_s[e]) * 4 + g];
    na_f[e][g * 4 + 0] = v.x; na_f[e][g * 4 + 1] = v.y;
    na_f[e][g * 4 + 2] = v.z; na_f[e][g * 4 + 3] = v.w;
  }

  // ---- fill chunk0 into Fb[0]: cols 0..63 = pos(16) + R0(16) + pairs 0,1 ----
  {
    int dp = dpos_s[e];
    v4h hp;
#pragma unroll
    for (int t = 0; t < 4; ++t)
      hp[t] = (_Float16)(W_pos[dp * 16 + g * 4 + t] + b_pos[g * 4 + t]);
    *(v4h*)&Fb[0][e][g * 4] = hp;
  }
  if (g == 0) {
    rbf16w(dnbr_s[e], &Fb[0][e][16]);
  } else if (g <= 2) {
    int pp = g - 1;
    rbf16w(pdist(qa_f[rr], na_f[e], pp), &Fb[0][e][32 + pp * 16]);
  }
  __syncthreads();

  // ---- GEMM: waves (mt: 64 rows) x (nh: 32 cols); 7 chunks of K=64 (last K=32),
  // fill of chunk c+1 (VALU/exp2) issued before MFMAs of chunk c -> pipe overlap ----
  int lane = tid & 63, wv = tid >> 6;
  int mt = wv & 1, nh = wv >> 1;
  int lm = lane & 15, lq = lane >> 4;
  const _Float16* bp0 = Wt + (size_t)(nh * 32 + lm) * NF + lq * 8;
  const _Float16* bp1 = bp0 + 16 * NF;
  v4f acc[4][2];
#pragma unroll
  for (int t = 0; t < 4; ++t) { acc[t][0] = (v4f){0,0,0,0}; acc[t][1] = (v4f){0,0,0,0}; }

#pragma unroll
  for (int c = 0; c < 7; ++c) {
    if (c < 6) {  // fill chunk c+1 (pairs 4c+2 .. 4c+5) into the other buffer
      int pp = 4 * c + 2 + g;
      if (pp < 24) {
        float d = pdist(qa_f[rr], na_f[e], pp);
        rbf16w(d, &Fb[(c & 1) ^ 1][e][g * 16]);
      }
    }
    __builtin_amdgcn_s_setprio(1);
#pragma unroll
    for (int kk = 0; kk < 2; ++kk) {
      if (c == 6 && kk == 1) break;  // last chunk is K=32
      v8h B0 = *(const v8h*)(bp0 + c * 64 + kk * 32);
      v8h B1 = *(const v8h*)(bp1 + c * 64 + kk * 32);
#pragma unroll
      for (int t = 0; t < 4; ++t) {
        v8h A = *(const v8h*)&Fb[c & 1][mt * 64 + t * 16 + lm][lq * 8 + kk * 32];
        acc[t][0] = __builtin_amdgcn_mfma_f32_16x16x32_f16(A, B0, acc[t][0], 0, 0, 0);
        acc[t][1] = __builtin_amdgcn_mfma_f32_16x16x32_f16(A, B1, acc[t][1], 0, 0, 0);
      }
    }
    __builtin_amdgcn_s_setprio(0);
    if (c < 6) __syncthreads();  // chunk c+1 filled, chunk c consumed
  }

  // ---- LayerNorm: per-row 32-col partials -> LDS -> combine -> store ----
#pragma unroll
  for (int t = 0; t < 4; ++t) {
#pragma unroll
    for (int r = 0; r < 4; ++r) {
      float s = acc[t][0][r] + acc[t][1][r];
      float q = acc[t][0][r] * acc[t][0][r] + acc[t][1][r] * acc[t][1][r];
#pragma unroll
      for (int off = 1; off <= 8; off <<= 1) {
        s += __shfl_xor(s, off);
        q += __shfl_xor(q, off);
      }
      if (lm == 0) {
        int row = mt * 64 + t * 16 + lq * 4 + r;
        partS[row][nh] = s;
        partQ[row][nh] = q;
      }
    }
  }
  __syncthreads();
  if (tid < 128) {
    float S = (partS[tid][0] + partS[tid][1]) + (partS[tid][2] + partS[tid][3]);
    float Q = (partQ[tid][0] + partQ[tid][1]) + (partQ[tid][2] + partQ[tid][3]);
    float mean = S * (1.0f / 128.0f);
    float var = Q * (1.0f / 128.0f) - mean * mean;
    mr[tid] = make_float2(mean, 1.0f / sqrtf(var + 1e-5f));
  }
  __syncthreads();
  float gm0 = gamma[nh * 32 + lm], gm1 = gamma[nh * 32 + 16 + lm];
  float bt0 = beta[nh * 32 + lm], bt1 = beta[nh * 32 + 16 + lm];
  float* op = outE + (size_t)bid * 128 * NOUT + nh * 32 + lm;
#pragma unroll
  for (int t = 0; t < 4; ++t) {
#pragma unroll
    for (int r = 0; r < 4; ++r) {
      int row = mt * 64 + t * 16 + lq * 4 + r;
      float2 m = mr[row];
      float* p = op + (size_t)row * NOUT;
      p[0]  = (acc[t][0][r] - m.x) * m.y * gm0 + bt0;
      p[16] = (acc[t][1][r] - m.x) * m.y * gm1 + bt1;
    }
  }
}

extern "C" void kernel_launch(void* const* d_in, const int* in_sizes, int n_in,
                              void* d_out, int out_size, void* d_ws, size_t ws_size,
                              hipStream_t stream) {
  const float* X = (const float*)d_in[0];
  const int* ridx = (const int*)d_in[2];
  const int* chain = (const int*)d_in[3];
  const float* W_pos = (const float*)d_in[4];
  const float* b_pos = (const float*)d_in[5];
  const float* W_edge = (const float*)d_in[6];
  const float* gamma = (const float*)d_in[7];
  const float* beta = (const float*)d_in[8];

  float* outE = (float*)d_out;
  float* outIdx = outE + (size_t)BB * LL * TOPK * NOUT;

  char* ws = (char*)d_ws;
  float4* atomsP = (float4*)(ws + OFF_ATOMS);
  float4* CaP = (float4*)(ws + OFF_CA);
  _Float16* Wt = (_Float16*)(ws + OFF_WT);

  prep_kernel<<<240, 256, 0, stream>>>(X, W_edge, atomsP, CaP, Wt);
  topk_kernel<<<BB * LL / 4, 256, 0, stream>>>(CaP, outIdx);
  edge_kernel<<<BB * LL / 4, 512, 0, stream>>>(atomsP, CaP, Wt, outIdx, ridx, chain,
                                               W_pos, b_pos, gamma, beta, outE);
}

// Round 8
// 221.618 us; speedup vs baseline: 1.0632x; 1.0632x over previous
//
#include <hip/hip_runtime.h>
#include <stdint.h>

typedef _Float16 v8h __attribute__((ext_vector_type(8)));
typedef _Float16 v4h __attribute__((ext_vector_type(4)));
typedef float v4f __attribute__((ext_vector_type(4)));

#define BB 4
#define LL 2048
#define TOPK 32
#define NF 416      // 16 pos + 16 R0 + 24*16 pair RBF
#define NOUT 128
#define NCAND 128
#define FBS 72      // Fb row stride in halves (144 B); data = 4 slots x 32 B

// 32B-slot XOR swizzle: feature slot s of row r lives at physical slot s^(r&3).
// Every write is one whole slot (16 halves) or inside one; every read is a
// 16 B half-slot -> bit-exact. Spreads A-read banks: 8-way -> 2-way (free).
#define FBSLOT(row, slot) ((((slot) ^ ((row) & 3)) << 4))

__device__ __constant__ int c_PA[24] = {0,2,3,4,1,1,1,1,0,0,0,4,4,3,0,2,3,4,2,3,4,2,3,2};
__device__ __constant__ int c_PB[24] = {0,2,3,4,0,2,3,4,2,3,4,2,3,2,1,1,1,1,0,0,0,4,4,3};

// ws layout (bytes)
#define OFF_ATOMS 0u            // B*L*16 f32 (4x float4/residue) = 524288 B
#define OFF_CA    524288u       // B*L float4                     = 131072 B
#define OFF_WT    655360u       // 128*416 f16                    = 106496 B

// wave-private monotone bin: exponent + 4 mantissa bits (16 bins/octave).
static __device__ inline int wbin(unsigned u) {
  int v = (int)(u >> 19) - 1870;
  v = v < 0 ? 0 : v;
  return v > 511 ? 511 : v;
}

// np-bit-matched distance: ((dx*dx+dy*dy)+dz*dz)+1e-6, no fma, exact sqrt
static __device__ inline float dist_np(float4 a, float4 b) {
#pragma clang fp contract(off)
  float dx = a.x - b.x, dy = a.y - b.y, dz = a.z - b.z;
  float s = ((dx * dx + dy * dy) + dz * dz) + 1e-6f;
  return sqrtf(s);
}

static __device__ inline unsigned long long umin64(unsigned long long a, unsigned long long b) {
  return a < b ? a : b;
}
static __device__ inline unsigned long long umax64(unsigned long long a, unsigned long long b) {
  return a > b ? a : b;
}

// windowed RBF: exp(-((d-mu_m)/1.25)^2), mu_m = 2 + (4/3)m, m=0..15.
// Only 8 consecutive m give values >= 2^-25 (f16-visible); rest exactly 0.
// Writes stay within one 32 B slot (dst = slot start, window [2*m0, 2*m0+16)).
static __device__ inline void rbf16w(float d, _Float16* dst) {
  v8h z = {};
  *(v8h*)dst = z;
  *(v8h*)(dst + 8) = z;
  float m0f = ceilf((d - 7.204f) * 0.75f);
  m0f = fmaxf(0.0f, fminf(8.0f, m0f));
  const float C  = 0.96089780f;   // sqrt(0.64 * log2(e))
  const float SC = 1.28119707f;   // (4/3) * C
  float a0 = d * C - 1.92179560f - m0f * SC;  // a at m = m0
  _Float16* p = dst + (int)m0f;
#pragma unroll
  for (int t = 0; t < 8; ++t) {
    float a = a0 - (float)t * SC;
    float v = __builtin_amdgcn_exp2f(-(a * a));
    p[t] = (_Float16)v;
  }
}

static __device__ inline float pdist(const float* qa, const float* nb, int pp) {
  int ia = c_PA[pp] * 3, ib = c_PB[pp] * 3;
  float dx = qa[ia] - nb[ib];
  float dy = qa[ia + 1] - nb[ib + 1];
  float dz = qa[ia + 2] - nb[ib + 2];
  return sqrtf(dx * dx + dy * dy + dz * dz + 1e-6f);
}

// ---------------- prep: atoms (16f rows), compact Ca float4, W_edge -> f16 T ----------------
__global__ __launch_bounds__(256) void prep_kernel(const float* __restrict__ X,
                                                   const float* __restrict__ W_edge,
                                                   float4* __restrict__ atomsP,
                                                   float4* __restrict__ CaP,
                                                   _Float16* __restrict__ Wt) {
  int idx = blockIdx.x * 256 + threadIdx.x;
  if (idx < BB * LL) {
    const float* xp = X + (size_t)idx * 12;
    float Nx = xp[0], Ny = xp[1], Nz = xp[2];
    float Cax = xp[3], Cay = xp[4], Caz = xp[5];
    float Cx = xp[6], Cy = xp[7], Cz = xp[8];
    float Ox = xp[9], Oy = xp[10], Oz = xp[11];
    float bx = Cax - Nx, by = Cay - Ny, bz = Caz - Nz;
    float cx = Cx - Cax, cy = Cy - Cay, cz = Cz - Caz;
    float ax = by * cz - bz * cy;
    float ay = bz * cx - bx * cz;
    float az = bx * cy - by * cx;
    float Cbx = -0.58273431f * ax + 0.56802827f * bx - 0.54067466f * cx + Cax;
    float Cby = -0.58273431f * ay + 0.56802827f * by - 0.54067466f * cy + Cay;
    float Cbz = -0.58273431f * az + 0.56802827f * bz - 0.54067466f * cz + Caz;
    // layout: [N(3) Ca(3) C(3) O(3) Cb(3) pad] as 4x float4
    atomsP[(size_t)idx * 4 + 0] = make_float4(Nx, Ny, Nz, Cax);
    atomsP[(size_t)idx * 4 + 1] = make_float4(Cay, Caz, Cx, Cy);
    atomsP[(size_t)idx * 4 + 2] = make_float4(Cz, Ox, Oy, Oz);
    atomsP[(size_t)idx * 4 + 3] = make_float4(Cbx, Cby, Cbz, 0.f);
    CaP[idx] = make_float4(Cax, Cay, Caz, 0.f);
  } else {
    int t = idx - BB * LL;
    if (t < NOUT * NF) {
      int n = t / NF;
      int k = t - n * NF;
      Wt[t] = (_Float16)W_edge[(size_t)k * NOUT + n];  // Wt[n][k] = W_edge[k][n]
    }
  }
}

// ---------------- top-32: ONE WAVE PER QUERY, zero block barriers.
// (R6-verified version, byte-identical: R7's sched_barrier batching regressed.) ----------------
__global__ __launch_bounds__(256) void topk_kernel(const float4* __restrict__ CaP,
                                                   float* __restrict__ outIdx) {
  __shared__ int hist[4][512];                   // 8 KB
  __shared__ unsigned long long cand[4][NCAND];  // 4 KB
  __shared__ int cnt[4];

  int tid = threadIdx.x;
  int lane = tid & 63, wid = tid >> 6;
  int q = blockIdx.x * 4 + wid;     // global query id
  int b = q >> 11;
  int i = q & (LL - 1);

  int* h = hist[wid];
  unsigned long long* cd = cand[wid];

  {  // zero hist (8 ints/lane) + init cand + cnt
    int4 z = make_int4(0, 0, 0, 0);
    ((int4*)h)[lane] = z;
    ((int4*)h)[lane + 64] = z;
    cd[lane] = ~0ull;
    cd[lane + 64] = ~0ull;
    if (lane == 0) cnt[wid] = 0;
  }

  const float4* Cb_ = CaP + (size_t)b * LL;
  float4 ci = Cb_[i];
  unsigned db[32];
#pragma unroll
  for (int t = 0; t < 32; ++t) {
    int j = lane + (t << 6);
    db[t] = __float_as_uint(dist_np(ci, Cb_[j]));
  }
  asm volatile("s_waitcnt lgkmcnt(0)" ::: "memory");  // zero/init done (wave-local)
#pragma unroll
  for (int t = 0; t < 32; ++t) {
    atomicAdd(&h[wbin(db[t])], 1);
  }
  asm volatile("s_waitcnt lgkmcnt(0)" ::: "memory");  // hist complete (wave-local)

  // scan: lane owns bins [lane*8, lane*8+8)
  int pb[8];
  int psum = 0;
  {
    int4 a0 = ((int4*)h)[lane * 2];
    int4 a1 = ((int4*)h)[lane * 2 + 1];
    pb[0] = a0.x; pb[1] = a0.y; pb[2] = a0.z; pb[3] = a0.w;
    pb[4] = a1.x; pb[5] = a1.y; pb[6] = a1.z; pb[7] = a1.w;
#pragma unroll
    for (int t = 0; t < 8; ++t) psum += pb[t];
  }
  int incl = psum;
#pragma unroll
  for (int off = 1; off < 64; off <<= 1) {
    int o = __shfl_up(incl, off);
    if (lane >= off) incl += o;
  }
  int base = incl - psum;  // exclusive prefix over 64 lane-ranges
  bool cross = (base < TOPK && incl >= TOPK);  // exactly one lane true
  int cb_local = 511;
  if (cross) {
    int run = base;
#pragma unroll
    for (int t = 0; t < 8; ++t) {
      if (run < TOPK && run + pb[t] >= TOPK) { cb_local = lane * 8 + t; break; }
      run += pb[t];
    }
  }
  unsigned long long cm = __ballot(cross);
  int src = __ffsll(cm) - 1;
  int cb = __shfl(cb_local, src);

  // collect keys with bin <= cb
#pragma unroll
  for (int t = 0; t < 32; ++t) {
    if (wbin(db[t]) <= cb) {
      int slot = atomicAdd(&cnt[wid], 1);
      if (slot < NCAND)
        cd[slot] = ((unsigned long long)db[t] << 32) | (unsigned)(lane + (t << 6));
    }
  }
  asm volatile("s_waitcnt lgkmcnt(0)" ::: "memory");  // collect visible (wave-local)

  int C = cnt[wid];
  unsigned long long x = cd[lane];
  if (C <= 64) {  // typical: C ~ 36-45; 21-step single-width bitonic sort
#pragma unroll
    for (int k = 2; k <= 64; k <<= 1) {
#pragma unroll
      for (int j = k >> 1; j >= 1; j >>= 1) {
        unsigned long long px = __shfl_xor(x, j);
        bool up = ((lane & k) == 0);
        bool low = ((lane & j) == 0);
        x = (low == up) ? umin64(x, px) : umax64(x, px);
      }
    }
  } else {  // fallback: full 128-candidate sort, 2/lane
    unsigned long long y = cd[lane + 64];
#pragma unroll
    for (int k = 2; k <= 128; k <<= 1) {
#pragma unroll
      for (int j = 64; j >= 1; j >>= 1) {
        if (j >= k) continue;
        if (j == 64) {
          unsigned long long mn = umin64(x, y), mx = umax64(x, y);
          x = mn; y = mx;
        } else {
          unsigned long long px = __shfl_xor(x, j);
          bool upx = ((lane & k) == 0);
          bool lowx = ((lane & j) == 0);
          x = (lowx == upx) ? umin64(x, px) : umax64(x, px);
          unsigned long long py = __shfl_xor(y, j);
          bool upy = (((lane + 64) & k) == 0);
          y = (lowx == upy) ? umin64(y, py) : umax64(y, py);
        }
      }
    }
  }
  if (lane < TOPK) {
    int j = (int)(x & 0xffffffffull);
    outIdx[(size_t)q * TOPK + lane] = (float)j;
  }
}

// ---------------- 4 residues/block: features -> f16 MFMA GEMM, double-buffered 64-col
// K-chunks; Fb slots XOR-swizzled by row (kills the ~8-way ds_read_b128 bank
// conflict, SQ_LDS_BANK_CONFLICT ~4M -> <1M). Structure otherwise frozen (R4/R5). ----------------
__global__ __launch_bounds__(512, 6) void edge_kernel(
    const float4* __restrict__ atomsP, const float4* __restrict__ CaP,
    const _Float16* __restrict__ Wt, const float* __restrict__ outIdxF,
    const int* __restrict__ ridx, const int* __restrict__ chain,
    const float* __restrict__ W_pos, const float* __restrict__ b_pos,
    const float* __restrict__ gamma, const float* __restrict__ beta,
    float* __restrict__ outE) {
  __shared__ __align__(16) _Float16 Fb[2][128][FBS];  // 36864 B, ping-pong K-chunks
  __shared__ float na_f[128][17];                     // neighbor atoms, padded stride
  __shared__ float qa_f[4][16];                       // query atoms per residue
  __shared__ float dnbr_s[128];
  __shared__ int dpos_s[128];
  __shared__ int nidx_s[128];
  __shared__ float partS[128][5];
  __shared__ float partQ[128][5];
  __shared__ float2 mr[128];

  int bid = blockIdx.x;          // group of 4 residues
  int b = bid >> 9;
  int tid = threadIdx.x;
  int g0 = bid * 4;              // first global residue (b*LL + i0 == bid*4)

  if (tid < 128) {
    int r = tid >> 5;
    int j = (int)outIdxF[(size_t)bid * 128 + tid];
    nidx_s[tid] = j;
    dnbr_s[tid] = dist_np(CaP[g0 + r], CaP[(size_t)b * LL + j]);
    int ri = ridx[g0 + r], rj = ridx[b * LL + j];
    int off = ri - rj + 32;
    off = off < 0 ? 0 : (off > 64 ? 64 : off);
    dpos_s[tid] = (chain[g0 + r] == chain[b * LL + j]) ? off : 65;
  } else if (tid < 144) {
    int q16 = tid - 128;
    int r = q16 >> 2, q = q16 & 3;
    float4 v = atomsP[(size_t)(g0 + r) * 4 + q];
    qa_f[r][q * 4 + 0] = v.x; qa_f[r][q * 4 + 1] = v.y;
    qa_f[r][q * 4 + 2] = v.z; qa_f[r][q * 4 + 3] = v.w;
  }
  __syncthreads();

  int e = tid >> 2, g = tid & 3;
  int rr = e >> 5;
  {  // neighbor atoms: one coalesced float4/thread; readers of na_f[e] are the same quad
    float4 v = atomsP[((size_t)b * LL + nidx_s[e]) * 4 + g];
    na_f[e][g * 4 + 0] = v.x; na_f[e][g * 4 + 1] = v.y;
    na_f[e][g * 4 + 2] = v.z; na_f[e][g * 4 + 3] = v.w;
  }

  // ---- fill chunk0 into Fb[0]: slots 0..3 = pos, R0, pair0, pair1 (swizzled) ----
  {
    int dp = dpos_s[e];
    v4h hp;
#pragma unroll
    for (int t = 0; t < 4; ++t)
      hp[t] = (_Float16)(W_pos[dp * 16 + g * 4 + t] + b_pos[g * 4 + t]);
    *(v4h*)&Fb[0][e][FBSLOT(e, 0) + g * 4] = hp;
  }
  if (g == 0) {
    rbf16w(dnbr_s[e], &Fb[0][e][FBSLOT(e, 1)]);
  } else if (g <= 2) {
    int pp = g - 1;
    rbf16w(pdist(qa_f[rr], na_f[e], pp), &Fb[0][e][FBSLOT(e, 2 + pp)]);
  }
  __syncthreads();

  // ---- GEMM: waves (mt: 64 rows) x (nh: 32 cols); 7 chunks of K=64 (last K=32),
  // fill of chunk c+1 (VALU/exp2) issued before MFMAs of chunk c -> pipe overlap ----
  int lane = tid & 63, wv = tid >> 6;
  int mt = wv & 1, nh = wv >> 1;
  int lm = lane & 15, lq = lane >> 4;
  const _Float16* bp0 = Wt + (size_t)(nh * 32 + lm) * NF + lq * 8;
  const _Float16* bp1 = bp0 + 16 * NF;
  v4f acc[4][2];
#pragma unroll
  for (int t = 0; t < 4; ++t) { acc[t][0] = (v4f){0,0,0,0}; acc[t][1] = (v4f){0,0,0,0}; }

#pragma unroll
  for (int c = 0; c < 7; ++c) {
    if (c < 6) {  // fill chunk c+1 (pairs 4c+2 .. 4c+5) into the other buffer, slot g
      int pp = 4 * c + 2 + g;
      if (pp < 24) {
        float d = pdist(qa_f[rr], na_f[e], pp);
        rbf16w(d, &Fb[(c & 1) ^ 1][e][FBSLOT(e, g)]);
      }
    }
    __builtin_amdgcn_s_setprio(1);
#pragma unroll
    for (int kk = 0; kk < 2; ++kk) {
      if (c == 6 && kk == 1) break;  // last chunk is K=32
      v8h B0 = *(const v8h*)(bp0 + c * 64 + kk * 32);
      v8h B1 = *(const v8h*)(bp1 + c * 64 + kk * 32);
#pragma unroll
      for (int t = 0; t < 4; ++t) {
        int row = mt * 64 + t * 16 + lm;
        v8h A = *(const v8h*)&Fb[c & 1][row][FBSLOT(row, (lq >> 1) + 2 * kk) + (lq & 1) * 8];
        acc[t][0] = __builtin_amdgcn_mfma_f32_16x16x32_f16(A, B0, acc[t][0], 0, 0, 0);
        acc[t][1] = __builtin_amdgcn_mfma_f32_16x16x32_f16(A, B1, acc[t][1], 0, 0, 0);
      }
    }
    __builtin_amdgcn_s_setprio(0);
    if (c < 6) __syncthreads();  // chunk c+1 filled, chunk c consumed
  }

  // ---- LayerNorm: per-row 32-col partials -> LDS -> combine -> store ----
#pragma unroll
  for (int t = 0; t < 4; ++t) {
#pragma unroll
    for (int r = 0; r < 4; ++r) {
      float s = acc[t][0][r] + acc[t][1][r];
      float q = acc[t][0][r] * acc[t][0][r] + acc[t][1][r] * acc[t][1][r];
#pragma unroll
      for (int off = 1; off <= 8; off <<= 1) {
        s += __shfl_xor(s, off);
        q += __shfl_xor(q, off);
      }
      if (lm == 0) {
        int row = mt * 64 + t * 16 + lq * 4 + r;
        partS[row][nh] = s;
        partQ[row][nh] = q;
      }
    }
  }
  __syncthreads();
  if (tid < 128) {
    float S = (partS[tid][0] + partS[tid][1]) + (partS[tid][2] + partS[tid][3]);
    float Q = (partQ[tid][0] + partQ[tid][1]) + (partQ[tid][2] + partQ[tid][3]);
    float mean = S * (1.0f / 128.0f);
    float var = Q * (1.0f / 128.0f) - mean * mean;
    mr[tid] = make_float2(mean, 1.0f / sqrtf(var + 1e-5f));
  }
  __syncthreads();
  float gm0 = gamma[nh * 32 + lm], gm1 = gamma[nh * 32 + 16 + lm];
  float bt0 = beta[nh * 32 + lm], bt1 = beta[nh * 32 + 16 + lm];
  float* op = outE + (size_t)bid * 128 * NOUT + nh * 32 + lm;
#pragma unroll
  for (int t = 0; t < 4; ++t) {
#pragma unroll
    for (int r = 0; r < 4; ++r) {
      int row = mt * 64 + t * 16 + lq * 4 + r;
      float2 m = mr[row];
      float* p = op + (size_t)row * NOUT;
      p[0]  = (acc[t][0][r] - m.x) * m.y * gm0 + bt0;
      p[16] = (acc[t][1][r] - m.x) * m.y * gm1 + bt1;
    }
  }
}

extern "C" void kernel_launch(void* const* d_in, const int* in_sizes, int n_in,
                              void* d_out, int out_size, void* d_ws, size_t ws_size,
                              hipStream_t stream) {
  const float* X = (const float*)d_in[0];
  const int* ridx = (const int*)d_in[2];
  const int* chain = (const int*)d_in[3];
  const float* W_pos = (const float*)d_in[4];
  const float* b_pos = (const float*)d_in[5];
  const float* W_edge = (const float*)d_in[6];
  const float* gamma = (const float*)d_in[7];
  const float* beta = (const float*)d_in[8];

  float* outE = (float*)d_out;
  float* outIdx = outE + (size_t)BB * LL * TOPK * NOUT;

  char* ws = (char*)d_ws;
  float4* atomsP = (float4*)(ws + OFF_ATOMS);
  float4* CaP = (float4*)(ws + OFF_CA);
  _Float16* Wt = (_Float16*)(ws + OFF_WT);

  prep_kernel<<<240, 256, 0, stream>>>(X, W_edge, atomsP, CaP, Wt);
  topk_kernel<<<BB * LL / 4, 256, 0, stream>>>(CaP, outIdx);
  edge_kernel<<<BB * LL / 4, 512, 0, stream>>>(atomsP, CaP, Wt, outIdx, ridx, chain,
                                               W_pos, b_pos, gamma, beta, outE);
}